// Round 11
// baseline (240.232 us; speedup 1.0000x reference)
//
#include <hip/hip_runtime.h>

typedef unsigned short u16;
typedef u16 us8 __attribute__((ext_vector_type(8)));
typedef u16 us4 __attribute__((ext_vector_type(4)));
typedef __bf16 bf16x8 __attribute__((ext_vector_type(8)));
typedef __bf16 bf16x4 __attribute__((ext_vector_type(4)));
typedef float f32x4 __attribute__((ext_vector_type(4)));

// ---------- helpers ----------
static __device__ __forceinline__ u16 f2bf(float f) {
  unsigned int u = __builtin_bit_cast(unsigned int, f);
  u += 0x7fffu + ((u >> 16) & 1u);   // RNE
  return (u16)(u >> 16);
}

static __device__ __forceinline__ float bf2f(u16 u) {
  return __builtin_bit_cast(float, (unsigned int)u << 16);
}

static __device__ __forceinline__ void gload16(const void* g, void* l) {
  __builtin_amdgcn_global_load_lds((const __attribute__((address_space(1))) void*)g,
                                   (__attribute__((address_space(3))) void*)l,
                                   16, 0, 0);
}

static __device__ __forceinline__ bf16x8 ldfrag_g(const u16* p) {
  return __builtin_bit_cast(bf16x8, *(const us8*)p);
}

template <int N> static __device__ __forceinline__ void vmwait() {
  asm volatile("s_waitcnt vmcnt(%0)" :: "n"(N) : "memory");
}

// ---------- K0: fp32 -> bf16 convert, all three tensors in one launch ----------
__global__ void cvt_all(const float* __restrict__ x, const float* __restrict__ wq,
                        const float* __restrict__ wp, u16* __restrict__ xb,
                        u16* __restrict__ wqb, u16* __restrict__ wpb) {
  int i = blockIdx.x * blockDim.x + threadIdx.x;
  const float* s; u16* d; int off;
  if (i < 786432)       { s = x;  d = xb;  off = i; }
  else if (i < 1007616) { s = wq; d = wqb; off = i - 786432; }
  else                  { s = wp; d = wpb; off = i - 1007616; }
  const float4* sp = (const float4*)s + (size_t)off * 2;
  float4 a = sp[0], b = sp[1];
  us8 o;
  o[0] = f2bf(a.x); o[1] = f2bf(a.y); o[2] = f2bf(a.z); o[3] = f2bf(a.w);
  o[4] = f2bf(b.x); o[5] = f2bf(b.y); o[6] = f2bf(b.z); o[7] = f2bf(b.w);
  *((us8*)d + off) = o;
}

// ---------- K1/K3: bf16 GEMM  C[M,Nc] = A[M,768] @ Bt[Nc,768]^T ----------
// R3's proven single-buffered loop. __launch_bounds__(256,5): VGPR<=102 ->
// 5 blocks/CU (LDS 32KB allows exactly 5) -> qkv's 1152-block grid fits in
// ONE concurrency round (capacity 1280), removing the 2x quantization tail.
// Inner loop keeps only b[4] live (a_m loaded per-m) to fit the reg budget.
// MODE 0: proj (f32+bias). MODE 1: qkv (bf16; V third written transposed to vt).
template <int MODE>
__global__ __launch_bounds__(256, 5) void gemm_bt(
    const u16* __restrict__ A, const u16* __restrict__ Bt,
    void* __restrict__ Cout, const float* __restrict__ bias,
    u16* __restrict__ vt, int Ncols) {
  __shared__ __align__(16) u16 As[128 * 64];
  __shared__ __align__(16) u16 Bs[128 * 64];
  const int tid = threadIdx.x;
  const int w = tid >> 6, l = tid & 63;
  const int fr = l & 15, fq = l >> 4;
  const int row0 = blockIdx.x * 128;
  const int col0 = blockIdx.y * 128;
  const int wr = (w >> 1) * 64, wc = (w & 1) * 64;
  const int lrow = l >> 3;            // 0..7 row within 8-row chunk
  const int lcol = (l & 7) * 8;       // bf16 elem offset (16B granules)

  f32x4 acc[4][4];
#pragma unroll
  for (int m = 0; m < 4; ++m)
#pragma unroll
    for (int n = 0; n < 4; ++n) acc[m][n] = f32x4{0.f, 0.f, 0.f, 0.f};

  for (int kt = 0; kt < 12; ++kt) {
    const int k0 = kt * 64;
    __syncthreads();
#pragma unroll
    for (int i = 0; i < 4; ++i) {
      int c = w * 4 + i;
      gload16(A  + (size_t)(row0 + c * 8 + lrow) * 768 + k0 + lcol, &As[c * 512]);
      gload16(Bt + (size_t)(col0 + c * 8 + lrow) * 768 + k0 + lcol, &Bs[c * 512]);
    }
    __syncthreads();
#pragma unroll
    for (int kk = 0; kk < 2; ++kk) {
      bf16x8 b[4];
#pragma unroll
      for (int n = 0; n < 4; ++n)
        b[n] = __builtin_bit_cast(bf16x8, *(const us8*)&Bs[(wc + n * 16 + fr) * 64 + kk * 32 + fq * 8]);
#pragma unroll
      for (int m = 0; m < 4; ++m) {
        bf16x8 a = __builtin_bit_cast(bf16x8, *(const us8*)&As[(wr + m * 16 + fr) * 64 + kk * 32 + fq * 8]);
#pragma unroll
        for (int n = 0; n < 4; ++n)
          acc[m][n] = __builtin_amdgcn_mfma_f32_16x16x32_bf16(a, b[n], acc[m][n], 0, 0, 0);
      }
    }
  }

  // epilogue. C/D layout: col = fr (c), rows = fq*4 + j.
  if (MODE == 0) {
#pragma unroll
    for (int m = 0; m < 4; ++m) {
      int r = row0 + wr + m * 16 + fq * 4;
#pragma unroll
      for (int n = 0; n < 4; ++n) {
        int c = col0 + wc + n * 16 + fr;
        float bb = bias[c];
#pragma unroll
        for (int j = 0; j < 4; ++j)
          ((float*)Cout)[(size_t)(r + j) * Ncols + c] = acc[m][n][j] + bb;
      }
    }
  } else if (col0 < 1536) {   // Q/K thirds: row-major bf16 qkv (block-uniform branch)
#pragma unroll
    for (int m = 0; m < 4; ++m) {
      int r = row0 + wr + m * 16 + fq * 4;
#pragma unroll
      for (int n = 0; n < 4; ++n) {
        int c = col0 + wc + n * 16 + fr;
#pragma unroll
        for (int j = 0; j < 4; ++j)
          ((u16*)Cout)[(size_t)(r + j) * Ncols + c] = f2bf(acc[m][n][j]);
      }
    }
  } else {                    // V third: write transposed vt[b*768 + (c-1536)][n]
    const int b = row0 >> 10;               // 128-row block lies in one batch
#pragma unroll
    for (int m = 0; m < 4; ++m) {
      int r = row0 + wr + m * 16 + fq * 4;  // rows r..r+3 -> consecutive n in vt
      int n0 = r & 1023;
#pragma unroll
      for (int n = 0; n < 4; ++n) {
        int c = col0 + wc + n * 16 + fr;
        f32x4 v = acc[m][n];
        us4 o2;
        o2[0] = f2bf(v[0]); o2[1] = f2bf(v[1]); o2[2] = f2bf(v[2]); o2[3] = f2bf(v[3]);
        *(us4*)&vt[(size_t)(b * 768 + (c - 1536)) * 1024 + n0] = o2;
      }
    }
  }
}

// ---------- K4: fused attention per (b,h, 32-row q-tile) ----------
// Swapped QK^T (mfma(K,Q)); K staged via double-buffered global_load_lds into
// the (not-yet-needed) P buffer (pre-swizzled source addrs, counted vmcnt,
// setprio). Normalized P lands in LDS once (bf16, XOR-swizzled); attn output
// written back from LDS fully-coalesced (full 128B lines, nt); PV reads same P.
__global__ __launch_bounds__(256, 2) void attn_fused(
    const u16* __restrict__ qkv, const u16* __restrict__ vt,
    float* __restrict__ attn_out, u16* __restrict__ ctx) {
  __shared__ __align__(16) u16 P[32 * 1024];  // swizzled bf16 P tile [q][key]
  __shared__ float red[2][4][32];
  const int tid = threadIdx.x;
  const int w = tid >> 6, l = tid & 63;
  const int fr = l & 15, fq = l >> 4;
  const int bh = blockIdx.x >> 5;
  const int qt = blockIdx.x & 31;
  const int b = bh / 12, h = bh - b * 12;
  const int q0 = qt * 32;

  // Q fragments (B-operand: lane supplies Q row fr), held in regs throughout
  bf16x8 aq[2][2];
#pragma unroll
  for (int m = 0; m < 2; ++m)
#pragma unroll
    for (int kk = 0; kk < 2; ++kk)
      aq[m][kk] = ldfrag_g(&qkv[(size_t)(b * 1024 + q0 + m * 16 + fr) * 2304 + h * 64 + kk * 32 + fq * 8]);
  vmwait<0>();                      // Q resident; keeps vmcnt accounting simple
  __builtin_amdgcn_sched_barrier(0);

  // ---- K staging setup: wave w owns bytes [w*16384, +16384) of P (2 x 8 KB bufs)
  char* kbase = (char*)P + w * 16384;
  const int kl = l >> 3;                               // row within 8-row stripe
  const int csrc = ((l & 7) ^ (kl & 7)) * 8;           // pre-swizzled source chunk (u16)
  const u16* kb = &qkv[(size_t)b * 1024 * 2304 + 768 + h * 64];
  const u16* ksrc = kb + (size_t)(w * 256 + kl) * 2304 + csrc;

  // acc[n][m][j] = S[key = w*256 + n*16 + fq*4 + j][q = m*16 + fr]
  f32x4 acc[16][2];
#pragma unroll
  for (int n = 0; n < 16; ++n)
#pragma unroll
    for (int m = 0; m < 2; ++m) acc[n][m] = f32x4{0.f, 0.f, 0.f, 0.f};

  // stage chunk 0 (64 keys = 8 x gload16)
#pragma unroll
  for (int i = 0; i < 8; ++i)
    gload16(ksrc + (size_t)(i * 8) * 2304, kbase + i * 1024);

#pragma unroll
  for (int g = 0; g < 4; ++g) {
    if (g < 3) {  // prefetch next chunk into other half
#pragma unroll
      for (int i = 0; i < 8; ++i)
        gload16(ksrc + (size_t)((g + 1) * 64 + i * 8) * 2304,
                kbase + ((g + 1) & 1) * 8192 + i * 1024);
      vmwait<8>();          // chunk g resident; next 8 still in flight
    } else {
      vmwait<0>();
    }
    __builtin_amdgcn_sched_barrier(0);
    char* buf = kbase + (g & 1) * 8192;
    __builtin_amdgcn_s_setprio(1);
#pragma unroll
    for (int n2 = 0; n2 < 4; ++n2) {
      int rowb = (n2 * 16 + fr) * 128;
#pragma unroll
      for (int kk = 0; kk < 2; ++kk) {
        int cidx = (kk * 4 + fq) ^ (fr & 7);
        bf16x8 bk = __builtin_bit_cast(bf16x8, *(const us8*)(buf + rowb + cidx * 16));
        int n = g * 4 + n2;
        acc[n][0] = __builtin_amdgcn_mfma_f32_16x16x32_bf16(bk, aq[0][kk], acc[n][0], 0, 0, 0);
        acc[n][1] = __builtin_amdgcn_mfma_f32_16x16x32_bf16(bk, aq[1][kk], acc[n][1], 0, 0, 0);
      }
    }
    __builtin_amdgcn_s_setprio(0);
  }

  // ---- softmax over keys for q-rows m*16+fr
  float mx[2];
#pragma unroll
  for (int m = 0; m < 2; ++m) mx[m] = -3.4e38f;
#pragma unroll
  for (int n = 0; n < 16; ++n)
#pragma unroll
    for (int m = 0; m < 2; ++m) {
      f32x4 v = acc[n][m];
      mx[m] = fmaxf(mx[m], fmaxf(fmaxf(v[0], v[1]), fmaxf(v[2], v[3])));
    }
#pragma unroll
  for (int m = 0; m < 2; ++m) {
    float v = mx[m];
    v = fmaxf(v, __shfl_xor(v, 16));
    v = fmaxf(v, __shfl_xor(v, 32));
    mx[m] = v;
  }
  if (fq == 0) {
#pragma unroll
    for (int m = 0; m < 2; ++m) red[0][w][m * 16 + fr] = mx[m];
  }
  __syncthreads();   // also fences all waves' K-staging reads before P overwrite
  const float C = 0.125f * 1.44269504f;
  float nrm[2];
#pragma unroll
  for (int m = 0; m < 2; ++m) {
    int r = m * 16 + fr;
    float rm = fmaxf(fmaxf(red[0][0][r], red[0][1][r]), fmaxf(red[0][2][r], red[0][3][r]));
    nrm[m] = -rm * C;
  }

  float sum[2] = {0.f, 0.f};
#pragma unroll
  for (int n = 0; n < 16; ++n)
#pragma unroll
    for (int m = 0; m < 2; ++m) {
#pragma unroll
      for (int j = 0; j < 4; ++j) {
        float p = exp2f(fmaf(acc[n][m][j], C, nrm[m]));
        acc[n][m][j] = p;
        sum[m] += p;
      }
    }
#pragma unroll
  for (int m = 0; m < 2; ++m) {
    float v = sum[m];
    v += __shfl_xor(v, 16);
    v += __shfl_xor(v, 32);
    sum[m] = v;
  }
  if (fq == 0) {
#pragma unroll
    for (int m = 0; m < 2; ++m) red[1][w][m * 16 + fr] = sum[m];
  }
  __syncthreads();
  float rinv[2];
#pragma unroll
  for (int m = 0; m < 2; ++m) {
    int r = m * 16 + fr;
    rinv[m] = 1.0f / (red[1][0][r] + red[1][1][r] + red[1][2][r] + red[1][3][r]);
  }

  // ---- normalize + P -> LDS (bf16x4 = 8B, swizzled); no global store here
#pragma unroll
  for (int n = 0; n < 16; ++n)
#pragma unroll
    for (int m = 0; m < 2; ++m) {
      int row = m * 16 + fr;
      int key = n * 16 + fq * 4;
      f32x4 v = acc[n][m];
      bf16x4 pk;
      pk[0] = (__bf16)(v[0] * rinv[m]); pk[1] = (__bf16)(v[1] * rinv[m]);
      pk[2] = (__bf16)(v[2] * rinv[m]); pk[3] = (__bf16)(v[3] * rinv[m]);
      int byte = (row * 2048 + (w * 256 + key) * 2) ^ ((row & 7) << 4);
      *(us4*)((char*)P + byte) = __builtin_bit_cast(us4, pk);
    }
  __syncthreads();

  // ---- attn writeback from LDS: thread t -> 4 f32 (16B); wave = 1KB contiguous
  float* aout = attn_out + (size_t)bh * (1024 * 1024) + (size_t)q0 * 1024;
#pragma unroll
  for (int it = 0; it < 32; ++it) {
    int idx = it * 256 + tid;        // 8192 f32x4-chunks over [32][1024]
    int row = idx >> 8;              // 256 chunks per row
    int ch = idx & 255;
    int byte = (row * 2048 + ch * 8) ^ ((row & 7) << 4);
    us4 p4 = *(const us4*)((const char*)P + byte);
    f32x4 o2;
    o2[0] = bf2f(p4[0]); o2[1] = bf2f(p4[1]); o2[2] = bf2f(p4[2]); o2[3] = bf2f(p4[3]);
    __builtin_nontemporal_store(o2, (f32x4*)(aout + (size_t)row * 1024 + ch * 4));
  }

  // ---- PV: out[32][w*16..+16] = P[32][1024] @ V[1024][64]
  f32x4 o2[2];
  o2[0] = f32x4{0.f, 0.f, 0.f, 0.f};
  o2[1] = f32x4{0.f, 0.f, 0.f, 0.f};
  const u16* vb = &vt[(size_t)bh * 64 * 1024 + (size_t)(w * 16 + fr) * 1024];
#pragma unroll 8
  for (int ks = 0; ks < 32; ++ks) {
    bf16x8 bv = ldfrag_g(&vb[ks * 32 + fq * 8]);
#pragma unroll
    for (int m = 0; m < 2; ++m) {
      int row = m * 16 + fr;
      int byte = (row * 2048 + (ks * 32 + fq * 8) * 2) ^ ((row & 7) << 4);
      bf16x8 ap = __builtin_bit_cast(bf16x8, *(const us8*)((const char*)P + byte));
      o2[m] = __builtin_amdgcn_mfma_f32_16x16x32_bf16(ap, bv, o2[m], 0, 0, 0);
    }
  }
#pragma unroll
  for (int m = 0; m < 2; ++m)
#pragma unroll
    for (int j = 0; j < 4; ++j) {
      int row = q0 + m * 16 + fq * 4 + j;
      int col = h * 64 + w * 16 + fr;
      ctx[(size_t)(b * 1024 + row) * 768 + col] = f2bf(o2[m][j]);
    }
}

// ---------- launch ----------
extern "C" void kernel_launch(void* const* d_in, const int* in_sizes, int n_in,
                              void* d_out, int out_size, void* d_ws, size_t ws_size,
                              hipStream_t stream) {
  const float* x      = (const float*)d_in[0];  // [8,1024,768]
  const float* qkv_w  = (const float*)d_in[1];  // [2304,768]
  const float* proj_w = (const float*)d_in[2];  // [768,768]
  const float* proj_b = (const float*)d_in[3];  // [768]
  float* out = (float*)d_out;                   // [8,1024,768]
  float* attn_out = out + 6291456;              // [8,12,1024,1024]

  char* ws = (char*)d_ws;
  u16* qkv_bf = (u16*)(ws);             // 8192x2304 (V third unused)  37,748,736 B
  u16* x_bf   = (u16*)(ws + 37748736);  // 8192x768         12,582,912 B
  u16* wq_bf  = (u16*)(ws + 50331648);  // 2304x768          3,538,944 B
  u16* wp_bf  = (u16*)(ws + 53870592);  // 768x768           1,179,648 B
  u16* vt_bf  = (u16*)(ws + 55050240);  // 96x64x1024       12,582,912 B
  u16* ctx_bf = (u16*)(ws + 67633152);  // 8192x768         12,582,912 B

  cvt_all<<<4224, 256, 0, stream>>>(x, qkv_w, proj_w, x_bf, wq_bf, wp_bf);

  gemm_bt<1><<<dim3(64, 18), 256, 0, stream>>>(x_bf, wq_bf, qkv_bf, nullptr, vt_bf, 2304);
  attn_fused<<<3072, 256, 0, stream>>>(qkv_bf, vt_bf, attn_out, ctx_bf);
  gemm_bt<0><<<dim3(64, 6), 256, 0, stream>>>(ctx_bf, wp_bf, out, proj_b, nullptr, 768);
}

// Round 12
// 190.222 us; speedup vs baseline: 1.2629x; 1.2629x over previous
//
#include <hip/hip_runtime.h>

typedef unsigned short u16;
typedef u16 us8 __attribute__((ext_vector_type(8)));
typedef u16 us4 __attribute__((ext_vector_type(4)));
typedef __bf16 bf16x8 __attribute__((ext_vector_type(8)));
typedef __bf16 bf16x4 __attribute__((ext_vector_type(4)));
typedef float f32x4 __attribute__((ext_vector_type(4)));

// ---------- helpers ----------
static __device__ __forceinline__ u16 f2bf(float f) {
  unsigned int u = __builtin_bit_cast(unsigned int, f);
  u += 0x7fffu + ((u >> 16) & 1u);   // RNE
  return (u16)(u >> 16);
}

static __device__ __forceinline__ float bf2f(u16 u) {
  return __builtin_bit_cast(float, (unsigned int)u << 16);
}

static __device__ __forceinline__ void gload16(const void* g, void* l) {
  __builtin_amdgcn_global_load_lds((const __attribute__((address_space(1))) void*)g,
                                   (__attribute__((address_space(3))) void*)l,
                                   16, 0, 0);
}

static __device__ __forceinline__ bf16x8 ldfrag_g(const u16* p) {
  return __builtin_bit_cast(bf16x8, *(const us8*)p);
}

template <int N> static __device__ __forceinline__ void vmwait() {
  asm volatile("s_waitcnt vmcnt(%0)" :: "n"(N) : "memory");
}

// ---------- K0: fp32 -> bf16 convert, all three tensors in one launch ----------
__global__ void cvt_all(const float* __restrict__ x, const float* __restrict__ wq,
                        const float* __restrict__ wp, u16* __restrict__ xb,
                        u16* __restrict__ wqb, u16* __restrict__ wpb) {
  int i = blockIdx.x * blockDim.x + threadIdx.x;
  const float* s; u16* d; int off;
  if (i < 786432)       { s = x;  d = xb;  off = i; }
  else if (i < 1007616) { s = wq; d = wqb; off = i - 786432; }
  else                  { s = wp; d = wpb; off = i - 1007616; }
  const float4* sp = (const float4*)s + (size_t)off * 2;
  float4 a = sp[0], b = sp[1];
  us8 o;
  o[0] = f2bf(a.x); o[1] = f2bf(a.y); o[2] = f2bf(a.z); o[3] = f2bf(a.w);
  o[4] = f2bf(b.x); o[5] = f2bf(b.y); o[6] = f2bf(b.z); o[7] = f2bf(b.w);
  *((us8*)d + off) = o;
}

// ---------- K1: qkv bf16 GEMM (R9-exact)  C[M,2304] = A[M,768] @ Bt[2304,768]^T
// 128x128 tile, single-buffered stage->barrier->compute->barrier loop.
// V third (cols >= 1536) written directly transposed into vt.
__global__ __launch_bounds__(256, 4) void gemm_qkv(
    const u16* __restrict__ A, const u16* __restrict__ Bt,
    u16* __restrict__ Cout, u16* __restrict__ vt) {
  __shared__ __align__(16) u16 As[128 * 64];
  __shared__ __align__(16) u16 Bs[128 * 64];
  const int tid = threadIdx.x;
  const int w = tid >> 6, l = tid & 63;
  const int fr = l & 15, fq = l >> 4;
  const int row0 = blockIdx.x * 128;
  const int col0 = blockIdx.y * 128;
  const int wr = (w >> 1) * 64, wc = (w & 1) * 64;
  const int lrow = l >> 3;            // 0..7 row within 8-row chunk
  const int lcol = (l & 7) * 8;       // bf16 elem offset (16B granules)

  f32x4 acc[4][4];
#pragma unroll
  for (int m = 0; m < 4; ++m)
#pragma unroll
    for (int n = 0; n < 4; ++n) acc[m][n] = f32x4{0.f, 0.f, 0.f, 0.f};

  for (int kt = 0; kt < 12; ++kt) {
    const int k0 = kt * 64;
    __syncthreads();
#pragma unroll
    for (int i = 0; i < 4; ++i) {
      int c = w * 4 + i;
      gload16(A  + (size_t)(row0 + c * 8 + lrow) * 768 + k0 + lcol, &As[c * 512]);
      gload16(Bt + (size_t)(col0 + c * 8 + lrow) * 768 + k0 + lcol, &Bs[c * 512]);
    }
    __syncthreads();
#pragma unroll
    for (int kk = 0; kk < 2; ++kk) {
      bf16x8 a[4], b[4];
#pragma unroll
      for (int m = 0; m < 4; ++m)
        a[m] = __builtin_bit_cast(bf16x8, *(const us8*)&As[(wr + m * 16 + fr) * 64 + kk * 32 + fq * 8]);
#pragma unroll
      for (int n = 0; n < 4; ++n)
        b[n] = __builtin_bit_cast(bf16x8, *(const us8*)&Bs[(wc + n * 16 + fr) * 64 + kk * 32 + fq * 8]);
#pragma unroll
      for (int m = 0; m < 4; ++m)
#pragma unroll
        for (int n = 0; n < 4; ++n)
          acc[m][n] = __builtin_amdgcn_mfma_f32_16x16x32_bf16(a[m], b[n], acc[m][n], 0, 0, 0);
    }
  }

  // epilogue. C/D layout: col = fr (c), rows = fq*4 + j.
  if (col0 < 1536) {          // Q/K thirds: row-major bf16 qkv
#pragma unroll
    for (int m = 0; m < 4; ++m) {
      int r = row0 + wr + m * 16 + fq * 4;
#pragma unroll
      for (int n = 0; n < 4; ++n) {
        int c = col0 + wc + n * 16 + fr;
#pragma unroll
        for (int j = 0; j < 4; ++j)
          Cout[(size_t)(r + j) * 2304 + c] = f2bf(acc[m][n][j]);
      }
    }
  } else {                    // V third: write transposed vt[b*768 + (c-1536)][n]
    const int b = row0 >> 10;               // 128-row block lies in one batch
#pragma unroll
    for (int m = 0; m < 4; ++m) {
      int r = row0 + wr + m * 16 + fq * 4;  // rows r..r+3 -> consecutive n in vt
      int n0 = r & 1023;
#pragma unroll
      for (int n = 0; n < 4; ++n) {
        int c = col0 + wc + n * 16 + fr;
        f32x4 v = acc[m][n];
        us4 o2;
        o2[0] = f2bf(v[0]); o2[1] = f2bf(v[1]); o2[2] = f2bf(v[2]); o2[3] = f2bf(v[3]);
        *(us4*)&vt[(size_t)(b * 768 + (c - 1536)) * 1024 + n0] = o2;
      }
    }
  }
}

// ---------- K3: proj GEMM, 64x128 tiles -> grid 768 = exactly 3 blocks/CU
// (vs 384 blocks = 1.5/CU at 128^2: half the CUs had NO co-resident block to
// hide the stage drain). Wave = 32 rows x 64 cols, acc[2][4] (32 VGPR).
__global__ __launch_bounds__(256, 4) void gemm_proj(
    const u16* __restrict__ A, const u16* __restrict__ Bt,
    float* __restrict__ Cout, const float* __restrict__ bias) {
  __shared__ __align__(16) u16 As[64 * 64];    //  8 KB
  __shared__ __align__(16) u16 Bs[128 * 64];   // 16 KB
  const int tid = threadIdx.x;
  const int w = tid >> 6, l = tid & 63;
  const int fr = l & 15, fq = l >> 4;
  const int row0 = blockIdx.x * 64;
  const int col0 = blockIdx.y * 128;
  const int wr = (w >> 1) * 32, wc = (w & 1) * 64;
  const int lrow = l >> 3;
  const int lcol = (l & 7) * 8;

  f32x4 acc[2][4];
#pragma unroll
  for (int m = 0; m < 2; ++m)
#pragma unroll
    for (int n = 0; n < 4; ++n) acc[m][n] = f32x4{0.f, 0.f, 0.f, 0.f};

  for (int kt = 0; kt < 12; ++kt) {
    const int k0 = kt * 64;
    __syncthreads();
    // 24 chunks (A: 8, B: 16), 6 per wave; branch is wave-uniform
#pragma unroll
    for (int i = 0; i < 6; ++i) {
      int c = w * 6 + i;
      if (c < 8)
        gload16(A  + (size_t)(row0 + c * 8 + lrow) * 768 + k0 + lcol, &As[c * 512]);
      else
        gload16(Bt + (size_t)(col0 + (c - 8) * 8 + lrow) * 768 + k0 + lcol, &Bs[(c - 8) * 512]);
    }
    __syncthreads();
#pragma unroll
    for (int kk = 0; kk < 2; ++kk) {
      bf16x8 a[2], b[4];
#pragma unroll
      for (int m = 0; m < 2; ++m)
        a[m] = __builtin_bit_cast(bf16x8, *(const us8*)&As[(wr + m * 16 + fr) * 64 + kk * 32 + fq * 8]);
#pragma unroll
      for (int n = 0; n < 4; ++n)
        b[n] = __builtin_bit_cast(bf16x8, *(const us8*)&Bs[(wc + n * 16 + fr) * 64 + kk * 32 + fq * 8]);
#pragma unroll
      for (int m = 0; m < 2; ++m)
#pragma unroll
        for (int n = 0; n < 4; ++n)
          acc[m][n] = __builtin_amdgcn_mfma_f32_16x16x32_bf16(a[m], b[n], acc[m][n], 0, 0, 0);
    }
  }

#pragma unroll
  for (int m = 0; m < 2; ++m) {
    int r = row0 + wr + m * 16 + fq * 4;
#pragma unroll
    for (int n = 0; n < 4; ++n) {
      int c = col0 + wc + n * 16 + fr;
      float bb = bias[c];
#pragma unroll
      for (int j = 0; j < 4; ++j)
        Cout[(size_t)(r + j) * 768 + c] = acc[m][n][j] + bb;
    }
  }
}

// ---------- K4: fused attention per (b,h, 32-row q-tile) — R9-exact ----------
__global__ __launch_bounds__(256, 2) void attn_fused(
    const u16* __restrict__ qkv, const u16* __restrict__ vt,
    float* __restrict__ attn_out, u16* __restrict__ ctx) {
  __shared__ __align__(16) u16 P[32 * 1024];  // swizzled bf16 P tile [q][key]
  __shared__ float red[2][4][32];
  const int tid = threadIdx.x;
  const int w = tid >> 6, l = tid & 63;
  const int fr = l & 15, fq = l >> 4;
  const int bh = blockIdx.x >> 5;
  const int qt = blockIdx.x & 31;
  const int b = bh / 12, h = bh - b * 12;
  const int q0 = qt * 32;

  // Q fragments (B-operand: lane supplies Q row fr), held in regs throughout
  bf16x8 aq[2][2];
#pragma unroll
  for (int m = 0; m < 2; ++m)
#pragma unroll
    for (int kk = 0; kk < 2; ++kk)
      aq[m][kk] = ldfrag_g(&qkv[(size_t)(b * 1024 + q0 + m * 16 + fr) * 2304 + h * 64 + kk * 32 + fq * 8]);
  vmwait<0>();                      // Q resident; keeps vmcnt accounting simple
  __builtin_amdgcn_sched_barrier(0);

  // ---- K staging setup: wave w owns bytes [w*16384, +16384) of P (2 x 8 KB bufs)
  char* kbase = (char*)P + w * 16384;
  const int kl = l >> 3;                               // row within 8-row stripe
  const int csrc = ((l & 7) ^ (kl & 7)) * 8;           // pre-swizzled source chunk (u16)
  const u16* kb = &qkv[(size_t)b * 1024 * 2304 + 768 + h * 64];
  const u16* ksrc = kb + (size_t)(w * 256 + kl) * 2304 + csrc;

  // acc[n][m][j] = S[key = w*256 + n*16 + fq*4 + j][q = m*16 + fr]
  f32x4 acc[16][2];
#pragma unroll
  for (int n = 0; n < 16; ++n)
#pragma unroll
    for (int m = 0; m < 2; ++m) acc[n][m] = f32x4{0.f, 0.f, 0.f, 0.f};

  // stage chunk 0 (64 keys = 8 x gload16)
#pragma unroll
  for (int i = 0; i < 8; ++i)
    gload16(ksrc + (size_t)(i * 8) * 2304, kbase + i * 1024);

#pragma unroll
  for (int g = 0; g < 4; ++g) {
    if (g < 3) {  // prefetch next chunk into other half
#pragma unroll
      for (int i = 0; i < 8; ++i)
        gload16(ksrc + (size_t)((g + 1) * 64 + i * 8) * 2304,
                kbase + ((g + 1) & 1) * 8192 + i * 1024);
      vmwait<8>();          // chunk g resident; next 8 still in flight
    } else {
      vmwait<0>();
    }
    __builtin_amdgcn_sched_barrier(0);
    char* buf = kbase + (g & 1) * 8192;
    __builtin_amdgcn_s_setprio(1);
#pragma unroll
    for (int n2 = 0; n2 < 4; ++n2) {
      int rowb = (n2 * 16 + fr) * 128;
#pragma unroll
      for (int kk = 0; kk < 2; ++kk) {
        int cidx = (kk * 4 + fq) ^ (fr & 7);
        bf16x8 bk = __builtin_bit_cast(bf16x8, *(const us8*)(buf + rowb + cidx * 16));
        int n = g * 4 + n2;
        acc[n][0] = __builtin_amdgcn_mfma_f32_16x16x32_bf16(bk, aq[0][kk], acc[n][0], 0, 0, 0);
        acc[n][1] = __builtin_amdgcn_mfma_f32_16x16x32_bf16(bk, aq[1][kk], acc[n][1], 0, 0, 0);
      }
    }
    __builtin_amdgcn_s_setprio(0);
  }

  // ---- softmax over keys for q-rows m*16+fr
  float mx[2];
#pragma unroll
  for (int m = 0; m < 2; ++m) mx[m] = -3.4e38f;
#pragma unroll
  for (int n = 0; n < 16; ++n)
#pragma unroll
    for (int m = 0; m < 2; ++m) {
      f32x4 v = acc[n][m];
      mx[m] = fmaxf(mx[m], fmaxf(fmaxf(v[0], v[1]), fmaxf(v[2], v[3])));
    }
#pragma unroll
  for (int m = 0; m < 2; ++m) {
    float v = mx[m];
    v = fmaxf(v, __shfl_xor(v, 16));
    v = fmaxf(v, __shfl_xor(v, 32));
    mx[m] = v;
  }
  if (fq == 0) {
#pragma unroll
    for (int m = 0; m < 2; ++m) red[0][w][m * 16 + fr] = mx[m];
  }
  __syncthreads();   // also fences all waves' K-staging reads before P overwrite
  const float C = 0.125f * 1.44269504f;
  float nrm[2];
#pragma unroll
  for (int m = 0; m < 2; ++m) {
    int r = m * 16 + fr;
    float rm = fmaxf(fmaxf(red[0][0][r], red[0][1][r]), fmaxf(red[0][2][r], red[0][3][r]));
    nrm[m] = -rm * C;
  }

  float sum[2] = {0.f, 0.f};
#pragma unroll
  for (int n = 0; n < 16; ++n)
#pragma unroll
    for (int m = 0; m < 2; ++m) {
#pragma unroll
      for (int j = 0; j < 4; ++j) {
        float p = exp2f(fmaf(acc[n][m][j], C, nrm[m]));
        acc[n][m][j] = p;
        sum[m] += p;
      }
    }
#pragma unroll
  for (int m = 0; m < 2; ++m) {
    float v = sum[m];
    v += __shfl_xor(v, 16);
    v += __shfl_xor(v, 32);
    sum[m] = v;
  }
  if (fq == 0) {
#pragma unroll
    for (int m = 0; m < 2; ++m) red[1][w][m * 16 + fr] = sum[m];
  }
  __syncthreads();
  float rinv[2];
#pragma unroll
  for (int m = 0; m < 2; ++m) {
    int r = m * 16 + fr;
    rinv[m] = 1.0f / (red[1][0][r] + red[1][1][r] + red[1][2][r] + red[1][3][r]);
  }

  // ---- normalize + P -> LDS (bf16x4 = 8B, swizzled); no global store here
#pragma unroll
  for (int n = 0; n < 16; ++n)
#pragma unroll
    for (int m = 0; m < 2; ++m) {
      int row = m * 16 + fr;
      int key = n * 16 + fq * 4;
      f32x4 v = acc[n][m];
      bf16x4 pk;
      pk[0] = (__bf16)(v[0] * rinv[m]); pk[1] = (__bf16)(v[1] * rinv[m]);
      pk[2] = (__bf16)(v[2] * rinv[m]); pk[3] = (__bf16)(v[3] * rinv[m]);
      int byte = (row * 2048 + (w * 256 + key) * 2) ^ ((row & 7) << 4);
      *(us4*)((char*)P + byte) = __builtin_bit_cast(us4, pk);
    }
  __syncthreads();

  // ---- attn writeback from LDS: thread t -> 4 f32 (16B); wave = 1KB contiguous
  float* aout = attn_out + (size_t)bh * (1024 * 1024) + (size_t)q0 * 1024;
#pragma unroll
  for (int it = 0; it < 32; ++it) {
    int idx = it * 256 + tid;        // 8192 f32x4-chunks over [32][1024]
    int row = idx >> 8;              // 256 chunks per row
    int ch = idx & 255;
    int byte = (row * 2048 + ch * 8) ^ ((row & 7) << 4);
    us4 p4 = *(const us4*)((const char*)P + byte);
    f32x4 o2;
    o2[0] = bf2f(p4[0]); o2[1] = bf2f(p4[1]); o2[2] = bf2f(p4[2]); o2[3] = bf2f(p4[3]);
    __builtin_nontemporal_store(o2, (f32x4*)(aout + (size_t)row * 1024 + ch * 4));
  }

  // ---- PV: out[32][w*16..+16] = P[32][1024] @ V[1024][64]
  f32x4 o2[2];
  o2[0] = f32x4{0.f, 0.f, 0.f, 0.f};
  o2[1] = f32x4{0.f, 0.f, 0.f, 0.f};
  const u16* vb = &vt[(size_t)bh * 64 * 1024 + (size_t)(w * 16 + fr) * 1024];
#pragma unroll 8
  for (int ks = 0; ks < 32; ++ks) {
    bf16x8 bv = ldfrag_g(&vb[ks * 32 + fq * 8]);
#pragma unroll
    for (int m = 0; m < 2; ++m) {
      int row = m * 16 + fr;
      int byte = (row * 2048 + (ks * 32 + fq * 8) * 2) ^ ((row & 7) << 4);
      bf16x8 ap = __builtin_bit_cast(bf16x8, *(const us8*)((const char*)P + byte));
      o2[m] = __builtin_amdgcn_mfma_f32_16x16x32_bf16(ap, bv, o2[m], 0, 0, 0);
    }
  }
#pragma unroll
  for (int m = 0; m < 2; ++m)
#pragma unroll
    for (int j = 0; j < 4; ++j) {
      int row = q0 + m * 16 + fq * 4 + j;
      int col = h * 64 + w * 16 + fr;
      ctx[(size_t)(b * 1024 + row) * 768 + col] = f2bf(o2[m][j]);
    }
}

// ---------- launch ----------
extern "C" void kernel_launch(void* const* d_in, const int* in_sizes, int n_in,
                              void* d_out, int out_size, void* d_ws, size_t ws_size,
                              hipStream_t stream) {
  const float* x      = (const float*)d_in[0];  // [8,1024,768]
  const float* qkv_w  = (const float*)d_in[1];  // [2304,768]
  const float* proj_w = (const float*)d_in[2];  // [768,768]
  const float* proj_b = (const float*)d_in[3];  // [768]
  float* out = (float*)d_out;                   // [8,1024,768]
  float* attn_out = out + 6291456;              // [8,12,1024,1024]

  char* ws = (char*)d_ws;
  u16* qkv_bf = (u16*)(ws);             // 8192x2304 (V third unused)  37,748,736 B
  u16* x_bf   = (u16*)(ws + 37748736);  // 8192x768         12,582,912 B
  u16* wq_bf  = (u16*)(ws + 50331648);  // 2304x768          3,538,944 B
  u16* wp_bf  = (u16*)(ws + 53870592);  // 768x768           1,179,648 B
  u16* vt_bf  = (u16*)(ws + 55050240);  // 96x64x1024       12,582,912 B
  u16* ctx_bf = (u16*)(ws + 67633152);  // 8192x768         12,582,912 B

  cvt_all<<<4224, 256, 0, stream>>>(x, qkv_w, proj_w, x_bf, wq_bf, wp_bf);

  gemm_qkv<<<dim3(64, 18), 256, 0, stream>>>(x_bf, wq_bf, qkv_bf, vt_bf);
  attn_fused<<<3072, 256, 0, stream>>>(qkv_bf, vt_bf, attn_out, ctx_bf);
  gemm_proj<<<dim3(128, 6), 256, 0, stream>>>(ctx_bf, wp_bf, out, proj_b);
}